// Round 2
// baseline (80.482 us; speedup 1.0000x reference)
//
#include <hip/hip_runtime.h>

// YOLO v1 loss, forward only. preds/labels: [16384, 7, 7, 30] f32 -> scalar f32.
// One thread per PAIR of cells: 240 B = 15 x float4, pair base is 16B-aligned.
#define NCELLS (16384 * 7 * 7)       // 802816
#define NPAIRS (NCELLS / 2)          // 401408
#define THREADS 256
#define NBLOCKS (NPAIRS / THREADS)   // 1568 exactly

__device__ __forceinline__ float cell_loss(const float* p, const float* l) {
    // IoU of both predicted boxes vs gt (l[0..3]), cxcywh format.
    float g_l = l[0] - l[2] * 0.5f, g_r = l[0] + l[2] * 0.5f;
    float g_t = l[1] - l[3] * 0.5f, g_b = l[1] + l[3] * 0.5f;
    float area_g = l[2] * l[3];

    float a_l = p[0] - p[2] * 0.5f, a_r = p[0] + p[2] * 0.5f;
    float a_t = p[1] - p[3] * 0.5f, a_b = p[1] + p[3] * 0.5f;
    float iw1 = fmaxf(fminf(a_r, g_r) - fmaxf(a_l, g_l), 0.0f);
    float ih1 = fmaxf(fminf(a_b, g_b) - fmaxf(a_t, g_t), 0.0f);
    float inter1 = iw1 * ih1;
    float iou1 = inter1 / (p[2] * p[3] + area_g - inter1 + 1e-10f);

    float b_l = p[5] - p[7] * 0.5f, b_r = p[5] + p[7] * 0.5f;
    float b_t = p[6] - p[8] * 0.5f, b_b = p[6] + p[8] * 0.5f;
    float iw2 = fmaxf(fminf(b_r, g_r) - fmaxf(b_l, g_l), 0.0f);
    float ih2 = fmaxf(fminf(b_b, g_b) - fmaxf(b_t, g_t), 0.0f);
    float inter2 = iw2 * ih2;
    float iou2 = inter2 / (p[7] * p[8] + area_g - inter2 + 1e-10f);

    bool r1 = iou1 > iou2;
    float rb0 = r1 ? p[0] : p[5];
    float rb1 = r1 ? p[1] : p[6];
    float rb2 = r1 ? p[2] : p[7];
    float rb3 = r1 ? p[3] : p[8];
    float rconf = r1 ? p[4] : p[9];
    float oconf = r1 ? p[9] : p[4];
    float riou = fmaxf(iou1, iou2);

    float dx = rb0 - l[0], dy = rb1 - l[1];
    float lxy = dx * dx + dy * dy;

    float spw = sqrtf(fmaxf(rb2, 1e-8f)), sgw = sqrtf(fmaxf(l[2], 1e-8f));
    float sph = sqrtf(fmaxf(rb3, 1e-8f)), sgh = sqrtf(fmaxf(l[3], 1e-8f));
    float dw = spw - sgw, dh = sph - sgh;
    float lwh = dw * dw + dh * dh;

    float dob = rconf - riou;

    float cls = 0.0f;
    #pragma unroll
    for (int c = 10; c < 30; ++c) {
        float d = p[c] - l[c];
        cls += d * d;
    }

    float obj = l[4];
    return obj * (5.0f * (lxy + lwh) + dob * dob + 0.5f * oconf * oconf + cls)
         + 0.5f * (1.0f - obj) * (p[4] * p[4] + p[9] * p[9]);
}

__device__ __forceinline__ float block_reduce(float acc) {
    #pragma unroll
    for (int off = 32; off > 0; off >>= 1) acc += __shfl_down(acc, off);
    __shared__ float s[THREADS / 64];
    int lane = threadIdx.x & 63, wid = threadIdx.x >> 6;
    if (lane == 0) s[wid] = acc;
    __syncthreads();
    float r = 0.0f;
    if (threadIdx.x == 0) {
        #pragma unroll
        for (int w = 0; w < THREADS / 64; ++w) r += s[w];
    }
    return r;
}

__global__ __launch_bounds__(THREADS) void yolo_partial(
        const float* __restrict__ preds, const float* __restrict__ labels,
        float* __restrict__ partials) {
    int pair = blockIdx.x * THREADS + threadIdx.x;   // < NPAIRS always (exact grid)
    const float4* pp = (const float4*)(preds  + (size_t)pair * 60);
    const float4* lp = (const float4*)(labels + (size_t)pair * 60);

    float p[60], l[60];
    #pragma unroll
    for (int i = 0; i < 15; ++i) {
        float4 v = pp[i];
        p[4 * i] = v.x; p[4 * i + 1] = v.y; p[4 * i + 2] = v.z; p[4 * i + 3] = v.w;
    }
    #pragma unroll
    for (int i = 0; i < 15; ++i) {
        float4 v = lp[i];
        l[4 * i] = v.x; l[4 * i + 1] = v.y; l[4 * i + 2] = v.z; l[4 * i + 3] = v.w;
    }

    float loss = cell_loss(p, l) + cell_loss(p + 30, l + 30);

    float r = block_reduce(loss);
    if (threadIdx.x == 0) partials[blockIdx.x] = r;
}

__global__ __launch_bounds__(THREADS) void yolo_final(
        const float* __restrict__ partials, float* __restrict__ out) {
    float acc = 0.0f;
    for (int i = threadIdx.x; i < NBLOCKS; i += THREADS) acc += partials[i];
    float r = block_reduce(acc);
    if (threadIdx.x == 0) out[0] = r * (1.0f / 16384.0f);
}

extern "C" void kernel_launch(void* const* d_in, const int* in_sizes, int n_in,
                              void* d_out, int out_size, void* d_ws, size_t ws_size,
                              hipStream_t stream) {
    const float* preds  = (const float*)d_in[0];
    const float* labels = (const float*)d_in[1];
    float* out = (float*)d_out;
    float* partials = (float*)d_ws;   // NBLOCKS * 4 B = 6.3 KB

    yolo_partial<<<NBLOCKS, THREADS, 0, stream>>>(preds, labels, partials);
    yolo_final<<<1, THREADS, 0, stream>>>(partials, out);
}

// Round 3
// 35.163 us; speedup vs baseline: 2.2888x; 2.2888x over previous
//
#include <hip/hip_runtime.h>

// YOLO v1 loss, forward only. preds/labels: [16384, 7, 7, 30] f32 -> scalar f32.
//
// Structure: persistent blocks (grid=256 = 1 block/CU), double-buffered LDS
// staging via async global_load_lds (width 16). Each tile = 256 cells:
// 30720 B per array, perfectly contiguous DMA; per-cell gather from LDS.
#define NCELLS (16384 * 7 * 7)          // 802816
#define THREADS 256
#define TILE_CELLS 256
#define FLOATS_PER_TILE (TILE_CELLS * 30)   // 7680 floats = 30720 B
#define NTILES (NCELLS / TILE_CELLS)        // 3136 exactly
#define GRID 256

__device__ __forceinline__ void gload16(const float* g, float* l) {
    // async global->LDS, 16 B per lane; LDS dest = uniform base + lane*16.
    __builtin_amdgcn_global_load_lds(
        (const __attribute__((address_space(1))) void*)g,
        (__attribute__((address_space(3))) void*)l, 16, 0, 0);
}

// Issue one tile's staging: 60 chunks of 256 floats (64 lanes x 16B each).
// Waves 0-1 stage preds (chunks 0..29), waves 2-3 stage labels (30..59).
__device__ __forceinline__ void stage_tile(const float* __restrict__ preds,
                                           const float* __restrict__ labels,
                                           float* sp, float* sl,
                                           int tile, int wid, int lane) {
    size_t base = (size_t)tile * FLOATS_PER_TILE;
    #pragma unroll
    for (int k = 0; k < 15; ++k) {
        int c = wid * 15 + k;   // 0..59, wave-uniform
        if (c < 30) {
            gload16(preds + base + (size_t)c * 256 + lane * 4, sp + c * 256);
        } else {
            int c2 = c - 30;
            gload16(labels + base + (size_t)c2 * 256 + lane * 4, sl + c2 * 256);
        }
    }
}

__device__ __forceinline__ float cell_loss(const float* p, const float* l) {
    float g_l = l[0] - l[2] * 0.5f, g_r = l[0] + l[2] * 0.5f;
    float g_t = l[1] - l[3] * 0.5f, g_b = l[1] + l[3] * 0.5f;
    float area_g = l[2] * l[3];

    float a_l = p[0] - p[2] * 0.5f, a_r = p[0] + p[2] * 0.5f;
    float a_t = p[1] - p[3] * 0.5f, a_b = p[1] + p[3] * 0.5f;
    float iw1 = fmaxf(fminf(a_r, g_r) - fmaxf(a_l, g_l), 0.0f);
    float ih1 = fmaxf(fminf(a_b, g_b) - fmaxf(a_t, g_t), 0.0f);
    float inter1 = iw1 * ih1;
    float iou1 = inter1 / (p[2] * p[3] + area_g - inter1 + 1e-10f);

    float b_l = p[5] - p[7] * 0.5f, b_r = p[5] + p[7] * 0.5f;
    float b_t = p[6] - p[8] * 0.5f, b_b = p[6] + p[8] * 0.5f;
    float iw2 = fmaxf(fminf(b_r, g_r) - fmaxf(b_l, g_l), 0.0f);
    float ih2 = fmaxf(fminf(b_b, g_b) - fmaxf(b_t, g_t), 0.0f);
    float inter2 = iw2 * ih2;
    float iou2 = inter2 / (p[7] * p[8] + area_g - inter2 + 1e-10f);

    bool r1 = iou1 > iou2;
    float rb0 = r1 ? p[0] : p[5];
    float rb1 = r1 ? p[1] : p[6];
    float rb2 = r1 ? p[2] : p[7];
    float rb3 = r1 ? p[3] : p[8];
    float rconf = r1 ? p[4] : p[9];
    float oconf = r1 ? p[9] : p[4];
    float riou = fmaxf(iou1, iou2);

    float dx = rb0 - l[0], dy = rb1 - l[1];
    float lxy = dx * dx + dy * dy;

    float spw = sqrtf(fmaxf(rb2, 1e-8f)), sgw = sqrtf(fmaxf(l[2], 1e-8f));
    float sph = sqrtf(fmaxf(rb3, 1e-8f)), sgh = sqrtf(fmaxf(l[3], 1e-8f));
    float dw = spw - sgw, dh = sph - sgh;
    float lwh = dw * dw + dh * dh;

    float dob = rconf - riou;

    float cls = 0.0f;
    #pragma unroll
    for (int c = 10; c < 30; ++c) {
        float d = p[c] - l[c];
        cls += d * d;
    }

    float obj = l[4];
    return obj * (5.0f * (lxy + lwh) + dob * dob + 0.5f * oconf * oconf + cls)
         + 0.5f * (1.0f - obj) * (p[4] * p[4] + p[9] * p[9]);
}

__device__ __forceinline__ float block_reduce(float acc) {
    #pragma unroll
    for (int off = 32; off > 0; off >>= 1) acc += __shfl_down(acc, off);
    __shared__ float s[THREADS / 64];
    int lane = threadIdx.x & 63, wid = threadIdx.x >> 6;
    if (lane == 0) s[wid] = acc;
    __syncthreads();
    float r = 0.0f;
    if (threadIdx.x == 0) {
        #pragma unroll
        for (int w = 0; w < THREADS / 64; ++w) r += s[w];
    }
    return r;
}

__global__ __launch_bounds__(THREADS, 1) void yolo_partial(
        const float* __restrict__ preds, const float* __restrict__ labels,
        float* __restrict__ partials) {
    __shared__ float sp[2][FLOATS_PER_TILE];   // 2 x 30720 B
    __shared__ float sl[2][FLOATS_PER_TILE];   // 2 x 30720 B   (total 120 KB)

    int lane = threadIdx.x & 63, wid = threadIdx.x >> 6;
    float acc = 0.0f;

    int tile = blockIdx.x;
    int buf = 0;
    if (tile < NTILES) stage_tile(preds, labels, sp[0], sl[0], tile, wid, lane);

    for (; tile < NTILES; tile += GRID, buf ^= 1) {
        // wait this wave's outstanding DMAs, then block-wide: buffer valid.
        asm volatile("s_waitcnt vmcnt(0)" ::: "memory");
        __syncthreads();
        // prefetch next tile into the other buffer (stays in flight during compute)
        int next = tile + GRID;
        if (next < NTILES)
            stage_tile(preds, labels, sp[buf ^ 1], sl[buf ^ 1], next, wid, lane);

        // gather this thread's cell from LDS (float2 reads; 8B-aligned)
        const float2* cp = (const float2*)(sp[buf] + threadIdx.x * 30);
        const float2* cl = (const float2*)(sl[buf] + threadIdx.x * 30);
        float p[30], l[30];
        #pragma unroll
        for (int i = 0; i < 15; ++i) {
            float2 v = cp[i]; p[2 * i] = v.x; p[2 * i + 1] = v.y;
        }
        #pragma unroll
        for (int i = 0; i < 15; ++i) {
            float2 v = cl[i]; l[2 * i] = v.x; l[2 * i + 1] = v.y;
        }
        acc += cell_loss(p, l);
    }

    float r = block_reduce(acc);
    if (threadIdx.x == 0) partials[blockIdx.x] = r;
}

__global__ __launch_bounds__(THREADS) void yolo_final(
        const float* __restrict__ partials, float* __restrict__ out) {
    float acc = (threadIdx.x < GRID) ? partials[threadIdx.x] : 0.0f;
    float r = block_reduce(acc);
    if (threadIdx.x == 0) out[0] = r * (1.0f / 16384.0f);
}

extern "C" void kernel_launch(void* const* d_in, const int* in_sizes, int n_in,
                              void* d_out, int out_size, void* d_ws, size_t ws_size,
                              hipStream_t stream) {
    const float* preds  = (const float*)d_in[0];
    const float* labels = (const float*)d_in[1];
    float* out = (float*)d_out;
    float* partials = (float*)d_ws;   // GRID * 4 B = 1 KB

    yolo_partial<<<GRID, THREADS, 0, stream>>>(preds, labels, partials);
    yolo_final<<<1, THREADS, 0, stream>>>(partials, out);
}